// Round 1
// baseline (297.874 us; speedup 1.0000x reference)
//
#include <hip/hip_runtime.h>

using bf16 = __bf16;
typedef __bf16 bf16x2 __attribute__((ext_vector_type(2)));
typedef __bf16 bf16x4v __attribute__((ext_vector_type(4)));
typedef __bf16 bf16x8 __attribute__((ext_vector_type(8)));
typedef float f32x4 __attribute__((ext_vector_type(4)));
typedef float floatx4 __attribute__((ext_vector_type(4)));

#define MFMA16(a, b, c) __builtin_amdgcn_mfma_f32_16x16x32_bf16((a), (b), (c), 0, 0, 0)

// ---------------- cast fp32 -> bf16 (4 elems/thread) ----------------
__global__ __launch_bounds__(256) void cast_kernel(const float* __restrict__ in,
                                                   bf16* __restrict__ out, int n4) {
  int i = blockIdx.x * 256 + threadIdx.x;
  if (i >= n4) return;
  floatx4 v = *(const floatx4*)(in + (size_t)i * 4);
  bf16x4v o;
  #pragma unroll
  for (int j = 0; j < 4; ++j) o[j] = (bf16)v[j];
  *(bf16x4v*)(out + (size_t)i * 4) = o;
}

// ---------------- GEMM: C[M][N] = A[M][K] * B[N][K]^T (both bf16, K-contig) ----------------
// 128x128 tile, BK=32, 4 waves, each wave 64x64 (4x4 fragments of 16x16x32 MFMA).
template <bool OUT_F32>
__global__ __launch_bounds__(256, 2) void gemm_bt(const bf16* __restrict__ A,
                                                  const bf16* __restrict__ B,
                                                  void* __restrict__ Cv,
                                                  int M, int N, int K) {
  __shared__ bf16 As[128 * 32];
  __shared__ bf16 Bs[128 * 32];
  const int t = threadIdx.x;
  const int l = t & 63;
  const int w = t >> 6;
  const int m0 = blockIdx.y * 128;
  const int n0 = blockIdx.x * 128;
  const int wr = (w >> 1) * 64;
  const int wc = (w & 1) * 64;
  const int lr = l & 15;
  const int lk = (l >> 4) * 8;

  f32x4 acc[4][4] = {};

  const int srow = t >> 2;        // 0..63
  const int scol = (t & 3) * 8;   // elem offset within BK

  for (int k0 = 0; k0 < K; k0 += 32) {
    __syncthreads();
    #pragma unroll
    for (int j = 0; j < 2; ++j) {
      const bf16* ga = A + (size_t)(m0 + j * 64 + srow) * K + k0 + scol;
      __builtin_amdgcn_global_load_lds(
          (const __attribute__((address_space(1))) void*)ga,
          (__attribute__((address_space(3))) void*)(As + (j * 64 + srow) * 32 + scol),
          16, 0, 0);
      const bf16* gb = B + (size_t)(n0 + j * 64 + srow) * K + k0 + scol;
      __builtin_amdgcn_global_load_lds(
          (const __attribute__((address_space(1))) void*)gb,
          (__attribute__((address_space(3))) void*)(Bs + (j * 64 + srow) * 32 + scol),
          16, 0, 0);
    }
    __syncthreads();
    bf16x8 af[4], bfr[4];
    #pragma unroll
    for (int i = 0; i < 4; ++i) af[i] = *(const bf16x8*)(As + (wr + i * 16 + lr) * 32 + lk);
    #pragma unroll
    for (int i = 0; i < 4; ++i) bfr[i] = *(const bf16x8*)(Bs + (wc + i * 16 + lr) * 32 + lk);
    #pragma unroll
    for (int i = 0; i < 4; ++i)
      #pragma unroll
      for (int j = 0; j < 4; ++j)
        acc[i][j] = MFMA16(af[i], bfr[j], acc[i][j]);
  }

  const int cr0 = (l >> 4) * 4;
  const int cc = l & 15;
  #pragma unroll
  for (int i = 0; i < 4; ++i) {
    #pragma unroll
    for (int j = 0; j < 4; ++j) {
      int row = m0 + wr + i * 16 + cr0;
      int col = n0 + wc + j * 16 + cc;
      #pragma unroll
      for (int r = 0; r < 4; ++r) {
        if constexpr (OUT_F32)
          ((float*)Cv)[(size_t)(row + r) * N + col] = acc[i][j][r];
        else
          ((bf16*)Cv)[(size_t)(row + r) * N + col] = (bf16)acc[i][j][r];
      }
    }
  }
}

// ---------------- RoPE in-place on q,k of qkv [4096][3072] ----------------
__global__ __launch_bounds__(256) void rope_kernel(bf16* __restrict__ qkv,
                                                   const int* __restrict__ pos) {
  int idx = blockIdx.x * 256 + threadIdx.x;  // [0, 4096*16*32)
  int i = idx & 31;
  int h = (idx >> 5) & 15;
  int row = idx >> 9;          // b*2048+s
  int s = row & 2047;
  float p = (float)pos[s];
  float freq = exp2f(-(float)i * (13.287712379549449f / 32.0f));  // theta^(-2i/64)
  float ang = p * freq;
  float sn, cs;
  sincosf(ang, &sn, &cs);
  size_t base = (size_t)row * 3072 + h * 64 + 2 * i;
  bf16x2 q = *(bf16x2*)(qkv + base);
  bf16x2 k = *(bf16x2*)(qkv + base + 1024);
  float q1 = (float)q[0], q2 = (float)q[1];
  float k1 = (float)k[0], k2 = (float)k[1];
  bf16x2 qo, ko;
  qo[0] = (bf16)(q1 * cs - q2 * sn);
  qo[1] = (bf16)(q1 * sn + q2 * cs);
  ko[0] = (bf16)(k1 * cs - k2 * sn);
  ko[1] = (bf16)(k1 * sn + k2 * cs);
  *(bf16x2*)(qkv + base) = qo;
  *(bf16x2*)(qkv + base + 1024) = ko;
}

// ---------------- causal flash attention ----------------
// grid: (S/64, B*H). 256 threads = 4 waves; wave w owns q rows [q0+16w, q0+16w+16).
// K-tile = 32 keys. Reads q/k/v strided from qkv (row stride 3072). Writes attn [4096][1024] bf16.
__global__ __launch_bounds__(256, 2) void fa_causal(const bf16* __restrict__ qkv,
                                                    bf16* __restrict__ attn) {
  const int bh = blockIdx.y;
  const int b = bh >> 4, h = bh & 15;
  const int q0 = blockIdx.x * 64;
  const int t = threadIdx.x, w = t >> 6, l = t & 63;
  const int lr = l & 15, lk = (l >> 4) * 8, cr0 = (l >> 4) * 4;

  __shared__ bf16 Ks[32 * 72];      // K tile, padded stride 72 (144B, 16B-aligned)
  __shared__ bf16 Vt[64 * 40];      // V tile transposed [d][key], stride 40 (80B)
  __shared__ bf16 Ps[4][16 * 40];   // per-wave P tile [q][key], stride 40

  const size_t rs = 3072;
  const bf16* Qg = qkv + (size_t)(b * 2048) * rs + h * 64;
  const bf16* Kg = Qg + 1024;
  const bf16* Vg = Qg + 2048;

  bf16x8 qf[2];
  #pragma unroll
  for (int kk = 0; kk < 2; ++kk)
    qf[kk] = *(const bf16x8*)(Qg + (size_t)(q0 + w * 16 + lr) * rs + kk * 32 + lk);

  f32x4 o[4] = {};
  float mrow[4], lrow[4];
  #pragma unroll
  for (int r = 0; r < 4; ++r) { mrow[r] = -1e30f; lrow[r] = 0.f; }

  const int nkt = (q0 + 64) >> 5;
  const int srow = t >> 3;        // 0..31 (key within tile)
  const int scol = (t & 7) * 8;   // d offset

  for (int kt = 0; kt < nkt; ++kt) {
    __syncthreads();  // prior iteration's PV reads done before restage
    {
      const int krow = kt * 32 + srow;
      bf16x8 kv = *(const bf16x8*)(Kg + (size_t)krow * rs + scol);
      *(bf16x8*)(&Ks[srow * 72 + scol]) = kv;
      bf16x8 vv = *(const bf16x8*)(Vg + (size_t)krow * rs + scol);
      #pragma unroll
      for (int e = 0; e < 8; ++e) Vt[(scol + e) * 40 + srow] = vv[e];
    }
    __syncthreads();

    // scores: 16q x 32k, two 16-col fragments
    f32x4 sc[2] = {};
    #pragma unroll
    for (int cf = 0; cf < 2; ++cf) {
      bf16x8 kb0 = *(const bf16x8*)(&Ks[(cf * 16 + lr) * 72 + lk]);
      bf16x8 kb1 = *(const bf16x8*)(&Ks[(cf * 16 + lr) * 72 + 32 + lk]);
      sc[cf] = MFMA16(qf[0], kb0, sc[cf]);
      sc[cf] = MFMA16(qf[1], kb1, sc[cf]);
    }

    // online softmax (fp32). C-frag rows: q = q0+16w+cr0+r, col k = kt*32+cf*16+lr
    float alpha[4];
    #pragma unroll
    for (int r = 0; r < 4; ++r) {
      int qg = q0 + w * 16 + cr0 + r;
      int k0g = kt * 32 + lr, k1g = k0g + 16;
      float s0 = (k0g <= qg) ? sc[0][r] * 0.125f : -1e30f;
      float s1 = (k1g <= qg) ? sc[1][r] * 0.125f : -1e30f;
      float mx = fmaxf(s0, s1);
      #pragma unroll
      for (int msk = 1; msk < 16; msk <<= 1) mx = fmaxf(mx, __shfl_xor(mx, msk, 64));
      float mnew = fmaxf(mrow[r], mx);
      float al = __expf(mrow[r] - mnew);
      float p0 = (k0g <= qg) ? __expf(s0 - mnew) : 0.f;  // predicated: fully-masked tile stays 0
      float p1 = (k1g <= qg) ? __expf(s1 - mnew) : 0.f;
      float rsum = p0 + p1;
      #pragma unroll
      for (int msk = 1; msk < 16; msk <<= 1) rsum += __shfl_xor(rsum, msk, 64);
      lrow[r] = lrow[r] * al + rsum;
      mrow[r] = mnew;
      alpha[r] = al;
      sc[0][r] = p0;
      sc[1][r] = p1;
    }

    // P (C-frag layout) -> LDS -> A-frag layout
    #pragma unroll
    for (int cf = 0; cf < 2; ++cf)
      #pragma unroll
      for (int r = 0; r < 4; ++r)
        Ps[w][(cr0 + r) * 40 + cf * 16 + lr] = (bf16)sc[cf][r];

    #pragma unroll
    for (int fd = 0; fd < 4; ++fd)
      #pragma unroll
      for (int r = 0; r < 4; ++r) o[fd][r] *= alpha[r];

    __syncthreads();  // P visible (uniform across waves)

    bf16x8 pa = *(const bf16x8*)(&Ps[w][lr * 40 + lk]);
    #pragma unroll
    for (int fd = 0; fd < 4; ++fd) {
      bf16x8 vb = *(const bf16x8*)(&Vt[(fd * 16 + lr) * 40 + lk]);
      o[fd] = MFMA16(pa, vb, o[fd]);
    }
  }

  #pragma unroll
  for (int fd = 0; fd < 4; ++fd) {
    #pragma unroll
    for (int r = 0; r < 4; ++r) {
      int qg = q0 + w * 16 + cr0 + r;
      int col = h * 64 + fd * 16 + lr;
      attn[(size_t)(b * 2048 + qg) * 1024 + col] = (bf16)(o[fd][r] / lrow[r]);
    }
  }
}

// ---------------- launch ----------------
extern "C" void kernel_launch(void* const* d_in, const int* in_sizes, int n_in,
                              void* d_out, int out_size, void* d_ws, size_t ws_size,
                              hipStream_t stream) {
  const float* x = (const float*)d_in[0];
  const int* pos = (const int*)d_in[1];
  const float* w_qkv = (const float*)d_in[2];
  const float* w_out = (const float*)d_in[3];
  float* out = (float*)d_out;

  char* ws = (char*)d_ws;
  bf16* xb   = (bf16*)(ws);                       // 4096*1024*2  = 8 MB
  bf16* wqb  = (bf16*)(ws + (8u << 20));          // 3072*1024*2  = 6 MB
  bf16* wob  = (bf16*)(ws + (14u << 20));         // 1024*1024*2  = 2 MB
  bf16* qkv  = (bf16*)(ws + (16u << 20));         // 4096*3072*2  = 24 MB
  bf16* attn = (bf16*)(ws + (40u << 20));         // 4096*1024*2  = 8 MB (total 48 MB)

  cast_kernel<<<4096, 256, 0, stream>>>(x, xb, 4194304 / 4);
  cast_kernel<<<3072, 256, 0, stream>>>(w_qkv, wqb, 3145728 / 4);
  cast_kernel<<<1024, 256, 0, stream>>>(w_out, wob, 1048576 / 4);

  dim3 g1(3072 / 128, 4096 / 128);
  gemm_bt<false><<<g1, 256, 0, stream>>>(xb, wqb, (void*)qkv, 4096, 3072, 1024);

  rope_kernel<<<8192, 256, 0, stream>>>(qkv, pos);

  dim3 gfa(2048 / 64, 32);
  fa_causal<<<gfa, 256, 0, stream>>>(qkv, attn);

  dim3 g2(1024 / 128, 4096 / 128);
  gemm_bt<true><<<g2, 256, 0, stream>>>(attn, wob, (void*)out, 4096, 1024, 1024);
}

// Round 2
// 177.969 us; speedup vs baseline: 1.6737x; 1.6737x over previous
//
#include <hip/hip_runtime.h>

using bf16 = __bf16;
typedef __bf16 bf16x2 __attribute__((ext_vector_type(2)));
typedef __bf16 bf16x4v __attribute__((ext_vector_type(4)));
typedef __bf16 bf16x8 __attribute__((ext_vector_type(8)));
typedef float f32x4 __attribute__((ext_vector_type(4)));
typedef float floatx4 __attribute__((ext_vector_type(4)));

#define MFMA16(a, b, c) __builtin_amdgcn_mfma_f32_16x16x32_bf16((a), (b), (c), 0, 0, 0)

// ---------------- cast fp32 -> bf16 (4 elems/thread) ----------------
__global__ __launch_bounds__(256) void cast_kernel(const float* __restrict__ in,
                                                   bf16* __restrict__ out, int n4) {
  int i = blockIdx.x * 256 + threadIdx.x;
  if (i >= n4) return;
  floatx4 v = *(const floatx4*)(in + (size_t)i * 4);
  bf16x4v o;
  #pragma unroll
  for (int j = 0; j < 4; ++j) o[j] = (bf16)v[j];
  *(bf16x4v*)(out + (size_t)i * 4) = o;
}

// ---------------- GEMM: C[M][N] = A[M][K] * B[N][K]^T (both bf16, K-contig) ----------------
template <bool OUT_F32>
__global__ __launch_bounds__(256, 2) void gemm_bt(const bf16* __restrict__ A,
                                                  const bf16* __restrict__ B,
                                                  void* __restrict__ Cv,
                                                  int M, int N, int K) {
  __shared__ bf16 As[128 * 32];
  __shared__ bf16 Bs[128 * 32];
  const int t = threadIdx.x;
  const int l = t & 63;
  const int w = t >> 6;
  const int m0 = blockIdx.y * 128;
  const int n0 = blockIdx.x * 128;
  const int wr = (w >> 1) * 64;
  const int wc = (w & 1) * 64;
  const int lr = l & 15;
  const int lk = (l >> 4) * 8;

  f32x4 acc[4][4] = {};

  const int srow = t >> 2;
  const int scol = (t & 3) * 8;

  for (int k0 = 0; k0 < K; k0 += 32) {
    __syncthreads();
    #pragma unroll
    for (int j = 0; j < 2; ++j) {
      const bf16* ga = A + (size_t)(m0 + j * 64 + srow) * K + k0 + scol;
      __builtin_amdgcn_global_load_lds(
          (const __attribute__((address_space(1))) void*)ga,
          (__attribute__((address_space(3))) void*)(As + (j * 64 + srow) * 32 + scol),
          16, 0, 0);
      const bf16* gb = B + (size_t)(n0 + j * 64 + srow) * K + k0 + scol;
      __builtin_amdgcn_global_load_lds(
          (const __attribute__((address_space(1))) void*)gb,
          (__attribute__((address_space(3))) void*)(Bs + (j * 64 + srow) * 32 + scol),
          16, 0, 0);
    }
    __syncthreads();
    bf16x8 af[4], bfr[4];
    #pragma unroll
    for (int i = 0; i < 4; ++i) af[i] = *(const bf16x8*)(As + (wr + i * 16 + lr) * 32 + lk);
    #pragma unroll
    for (int i = 0; i < 4; ++i) bfr[i] = *(const bf16x8*)(Bs + (wc + i * 16 + lr) * 32 + lk);
    #pragma unroll
    for (int i = 0; i < 4; ++i)
      #pragma unroll
      for (int j = 0; j < 4; ++j)
        acc[i][j] = MFMA16(af[i], bfr[j], acc[i][j]);
  }

  const int cr0 = (l >> 4) * 4;
  const int cc = l & 15;
  #pragma unroll
  for (int i = 0; i < 4; ++i) {
    #pragma unroll
    for (int j = 0; j < 4; ++j) {
      int row = m0 + wr + i * 16 + cr0;
      int col = n0 + wc + j * 16 + cc;
      #pragma unroll
      for (int r = 0; r < 4; ++r) {
        if constexpr (OUT_F32)
          ((float*)Cv)[(size_t)(row + r) * N + col] = acc[i][j][r];
        else
          ((bf16*)Cv)[(size_t)(row + r) * N + col] = (bf16)acc[i][j][r];
      }
    }
  }
}

// ---------------- RoPE in-place on q,k of qkv [4096][3072] ----------------
__global__ __launch_bounds__(256) void rope_kernel(bf16* __restrict__ qkv,
                                                   const int* __restrict__ pos) {
  int idx = blockIdx.x * 256 + threadIdx.x;
  int i = idx & 31;
  int h = (idx >> 5) & 15;
  int row = idx >> 9;
  int s = row & 2047;
  float p = (float)pos[s];
  float freq = exp2f(-(float)i * (13.287712379549449f / 32.0f));
  float ang = p * freq;
  float sn, cs;
  sincosf(ang, &sn, &cs);
  size_t base = (size_t)row * 3072 + h * 64 + 2 * i;
  bf16x2 q = *(bf16x2*)(qkv + base);
  bf16x2 k = *(bf16x2*)(qkv + base + 1024);
  float q1 = (float)q[0], q2 = (float)q[1];
  float k1 = (float)k[0], k2 = (float)k[1];
  bf16x2 qo, ko;
  qo[0] = (bf16)(q1 * cs - q2 * sn);
  qo[1] = (bf16)(q1 * sn + q2 * cs);
  ko[0] = (bf16)(k1 * cs - k2 * sn);
  ko[1] = (bf16)(k1 * sn + k2 * cs);
  *(bf16x2*)(qkv + base) = qo;
  *(bf16x2*)(qkv + base + 1024) = ko;
}

// ---------------- causal flash attention (swapped-operand, lane-local softmax) ----------
// grid: (S/64, B*H), 256 thr = 4 waves, wave w owns q rows [q0+16w, q0+16w+16).
// Scores computed as S^T = mfma(K, Q): lane owns query col (l&15), keys in regs.
// PV as O^T = mfma(V^T, P^T): rescale is lane-uniform; epilogue transposes via LDS.
__global__ __launch_bounds__(256, 2) void fa_causal(const bf16* __restrict__ qkv,
                                                    bf16* __restrict__ attn) {
  const int bh = blockIdx.y;
  const int b = bh >> 4, h = bh & 15;
  const int q0 = (gridDim.x - 1 - blockIdx.x) * 64;  // heavy blocks dispatch first
  const int t = threadIdx.x, w = t >> 6, l = t & 63;
  const int lq = l & 15;      // query (col) index within 16
  const int g = l >> 4;       // lane group 0..3
  const int lk = g * 8;       // key/d chunk base

  __shared__ bf16 Ks[32 * 72];     // K tile [key][d], stride 72
  __shared__ bf16 Vt[64 * 40];     // V^T [d][key], key-position XOR-swizzled
  __shared__ bf16 Ps[4][16 * 40];  // per-wave P^T staging [q][key]
  __shared__ bf16 Os[4][16 * 72];  // per-wave epilogue transpose [q][d]

  const size_t rs = 3072;
  const bf16* Qg = qkv + (size_t)(b * 2048) * rs + h * 64;
  const bf16* Kg = Qg + 1024;
  const bf16* Vg = Qg + 2048;

  const int qg = q0 + w * 16 + lq;

  bf16x8 qf[2];
  #pragma unroll
  for (int kk = 0; kk < 2; ++kk)
    qf[kk] = *(const bf16x8*)(Qg + (size_t)qg * rs + kk * 32 + lk);

  f32x4 o[4] = {};
  float mrow = -1e30f, lrow = 0.f;

  const int nkt = (q0 + 64) >> 5;
  const int srow = t >> 3;         // key row 0..31
  const int scol = (t & 7) * 8;    // d chunk
  const int vswz = (t & 3) << 3;   // = ((d>>3)&3)<<3 for d in [scol, scol+8)

  for (int kt = 0; kt < nkt; ++kt) {
    __syncthreads();  // all reads of Ks/Vt from previous tile done
    {
      const int krow = kt * 32 + srow;
      bf16x8 kv = *(const bf16x8*)(Kg + (size_t)krow * rs + scol);
      *(bf16x8*)(&Ks[srow * 72 + scol]) = kv;
      bf16x8 vv = *(const bf16x8*)(Vg + (size_t)krow * rs + scol);
      #pragma unroll
      for (int e = 0; e < 8; ++e)
        Vt[(scol + e) * 40 + (srow ^ vswz)] = vv[e];
    }
    __syncthreads();

    if (kt * 32 <= q0 + w * 16 + 15) {  // wave-uniform: tile not fully masked
      // S^T fragments: row = key (kf*16 + g*4 + r), col = query (lq)
      f32x4 sc[2] = {};
      #pragma unroll
      for (int kf = 0; kf < 2; ++kf) {
        bf16x8 kb0 = *(const bf16x8*)(&Ks[(kf * 16 + lq) * 72 + lk]);
        bf16x8 kb1 = *(const bf16x8*)(&Ks[(kf * 16 + lq) * 72 + 32 + lk]);
        sc[kf] = MFMA16(kb0, qf[0], sc[kf]);
        sc[kf] = MFMA16(kb1, qf[1], sc[kf]);
      }

      // lane-local softmax: 8 key-scores per lane, reduce with 2 shfls
      float pv[8];
      float mx = -1e30f;
      #pragma unroll
      for (int kf = 0; kf < 2; ++kf)
        #pragma unroll
        for (int r = 0; r < 4; ++r) {
          int key = kt * 32 + kf * 16 + g * 4 + r;
          float s = (key <= qg) ? sc[kf][r] * 0.125f : -1e30f;
          pv[kf * 4 + r] = s;
          mx = fmaxf(mx, s);
        }
      mx = fmaxf(mx, __shfl_xor(mx, 16, 64));
      mx = fmaxf(mx, __shfl_xor(mx, 32, 64));
      float mnew = fmaxf(mrow, mx);
      float al = __expf(mrow - mnew);
      float rsum = 0.f;
      #pragma unroll
      for (int i = 0; i < 8; ++i) {
        float p = __expf(pv[i] - mnew);  // masked -> exp(-huge) = 0
        pv[i] = p;
        rsum += p;
      }
      rsum += __shfl_xor(rsum, 16, 64);
      rsum += __shfl_xor(rsum, 32, 64);
      lrow = lrow * al + rsum;
      mrow = mnew;

      #pragma unroll
      for (int fd = 0; fd < 4; ++fd)
        #pragma unroll
        for (int r = 0; r < 4; ++r) o[fd][r] *= al;

      // P^T relayout (wave-local, no barrier): write [q][key], read B-frag
      #pragma unroll
      for (int kf = 0; kf < 2; ++kf)
        #pragma unroll
        for (int r = 0; r < 4; ++r)
          Ps[w][lq * 40 + kf * 16 + g * 4 + r] = (bf16)pv[kf * 4 + r];
      asm volatile("" ::: "memory");
      bf16x8 pb = *(const bf16x8*)(&Ps[w][lq * 40 + lk]);

      #pragma unroll
      for (int fd = 0; fd < 4; ++fd) {
        int d = fd * 16 + lq;
        int p = ((d >> 3) & 3) << 3;
        bf16x8 vb = *(const bf16x8*)(&Vt[d * 40 + (lk ^ p)]);
        o[fd] = MFMA16(vb, pb, o[fd]);  // O^T: row=d, col=q
      }
    }
  }

  // epilogue: O^T regs -> [q][d] LDS -> coalesced b128 stores
  float inv = 1.0f / lrow;
  #pragma unroll
  for (int fd = 0; fd < 4; ++fd)
    #pragma unroll
    for (int r = 0; r < 4; ++r)
      Os[w][lq * 72 + fd * 16 + g * 4 + r] = (bf16)(o[fd][r] * inv);
  asm volatile("" ::: "memory");
  #pragma unroll
  for (int pp = 0; pp < 2; ++pp) {
    int row = pp * 8 + (l >> 3);
    int c = (l & 7) * 8;
    bf16x8 v = *(const bf16x8*)(&Os[w][row * 72 + c]);
    *(bf16x8*)(&attn[(size_t)(b * 2048 + q0 + w * 16 + row) * 1024 + h * 64 + c]) = v;
  }
}

// ---------------- launch ----------------
extern "C" void kernel_launch(void* const* d_in, const int* in_sizes, int n_in,
                              void* d_out, int out_size, void* d_ws, size_t ws_size,
                              hipStream_t stream) {
  const float* x = (const float*)d_in[0];
  const int* pos = (const int*)d_in[1];
  const float* w_qkv = (const float*)d_in[2];
  const float* w_out = (const float*)d_in[3];
  float* out = (float*)d_out;

  char* ws = (char*)d_ws;
  bf16* xb   = (bf16*)(ws);
  bf16* wqb  = (bf16*)(ws + (8u << 20));
  bf16* wob  = (bf16*)(ws + (14u << 20));
  bf16* qkv  = (bf16*)(ws + (16u << 20));
  bf16* attn = (bf16*)(ws + (40u << 20));

  cast_kernel<<<4096, 256, 0, stream>>>(x, xb, 4194304 / 4);
  cast_kernel<<<3072, 256, 0, stream>>>(w_qkv, wqb, 3145728 / 4);
  cast_kernel<<<1024, 256, 0, stream>>>(w_out, wob, 1048576 / 4);

  dim3 g1(3072 / 128, 4096 / 128);
  gemm_bt<false><<<g1, 256, 0, stream>>>(xb, wqb, (void*)qkv, 4096, 3072, 1024);

  rope_kernel<<<8192, 256, 0, stream>>>(qkv, pos);

  dim3 gfa(2048 / 64, 32);
  fa_causal<<<gfa, 256, 0, stream>>>(qkv, attn);

  dim3 g2(1024 / 128, 4096 / 128);
  gemm_bt<true><<<g2, 256, 0, stream>>>(attn, wob, (void*)out, 4096, 1024, 1024);
}

// Round 3
// 176.678 us; speedup vs baseline: 1.6860x; 1.0073x over previous
//
#include <hip/hip_runtime.h>

using bf16 = __bf16;
typedef __bf16 bf16x2 __attribute__((ext_vector_type(2)));
typedef __bf16 bf16x4v __attribute__((ext_vector_type(4)));
typedef __bf16 bf16x8 __attribute__((ext_vector_type(8)));
typedef float f32x4 __attribute__((ext_vector_type(4)));
typedef float floatx4 __attribute__((ext_vector_type(4)));

#define MFMA16(a, b, c) __builtin_amdgcn_mfma_f32_16x16x32_bf16((a), (b), (c), 0, 0, 0)

// ---------------- cast fp32 -> bf16 (4 elems/thread) ----------------
__global__ __launch_bounds__(256) void cast_kernel(const float* __restrict__ in,
                                                   bf16* __restrict__ out, int n4) {
  int i = blockIdx.x * 256 + threadIdx.x;
  if (i >= n4) return;
  floatx4 v = *(const floatx4*)(in + (size_t)i * 4);
  bf16x4v o;
  #pragma unroll
  for (int j = 0; j < 4; ++j) o[j] = (bf16)v[j];
  *(bf16x4v*)(out + (size_t)i * 4) = o;
}

// ---------------- GEMM: C[M][N] = A[M][K] * B[N][K]^T (both bf16, K-contig) ----------------
template <bool OUT_F32>
__global__ __launch_bounds__(256, 2) void gemm_bt(const bf16* __restrict__ A,
                                                  const bf16* __restrict__ B,
                                                  void* __restrict__ Cv,
                                                  int M, int N, int K) {
  __shared__ bf16 As[128 * 32];
  __shared__ bf16 Bs[128 * 32];
  const int t = threadIdx.x;
  const int l = t & 63;
  const int w = t >> 6;
  const int m0 = blockIdx.y * 128;
  const int n0 = blockIdx.x * 128;
  const int wr = (w >> 1) * 64;
  const int wc = (w & 1) * 64;
  const int lr = l & 15;
  const int lk = (l >> 4) * 8;

  f32x4 acc[4][4] = {};

  const int srow = t >> 2;
  const int scol = (t & 3) * 8;

  for (int k0 = 0; k0 < K; k0 += 32) {
    __syncthreads();
    #pragma unroll
    for (int j = 0; j < 2; ++j) {
      const bf16* ga = A + (size_t)(m0 + j * 64 + srow) * K + k0 + scol;
      __builtin_amdgcn_global_load_lds(
          (const __attribute__((address_space(1))) void*)ga,
          (__attribute__((address_space(3))) void*)(As + (j * 64 + srow) * 32 + scol),
          16, 0, 0);
      const bf16* gb = B + (size_t)(n0 + j * 64 + srow) * K + k0 + scol;
      __builtin_amdgcn_global_load_lds(
          (const __attribute__((address_space(1))) void*)gb,
          (__attribute__((address_space(3))) void*)(Bs + (j * 64 + srow) * 32 + scol),
          16, 0, 0);
    }
    __syncthreads();
    bf16x8 af[4], bfr[4];
    #pragma unroll
    for (int i = 0; i < 4; ++i) af[i] = *(const bf16x8*)(As + (wr + i * 16 + lr) * 32 + lk);
    #pragma unroll
    for (int i = 0; i < 4; ++i) bfr[i] = *(const bf16x8*)(Bs + (wc + i * 16 + lr) * 32 + lk);
    #pragma unroll
    for (int i = 0; i < 4; ++i)
      #pragma unroll
      for (int j = 0; j < 4; ++j)
        acc[i][j] = MFMA16(af[i], bfr[j], acc[i][j]);
  }

  const int cr0 = (l >> 4) * 4;
  const int cc = l & 15;
  #pragma unroll
  for (int i = 0; i < 4; ++i) {
    #pragma unroll
    for (int j = 0; j < 4; ++j) {
      int row = m0 + wr + i * 16 + cr0;
      int col = n0 + wc + j * 16 + cc;
      #pragma unroll
      for (int r = 0; r < 4; ++r) {
        if constexpr (OUT_F32)
          ((float*)Cv)[(size_t)(row + r) * N + col] = acc[i][j][r];
        else
          ((bf16*)Cv)[(size_t)(row + r) * N + col] = (bf16)acc[i][j][r];
      }
    }
  }
}

// ---------------- RoPE in-place on q,k of qkv [4096][3072] ----------------
__global__ __launch_bounds__(256) void rope_kernel(bf16* __restrict__ qkv,
                                                   const int* __restrict__ pos) {
  int idx = blockIdx.x * 256 + threadIdx.x;
  int i = idx & 31;
  int h = (idx >> 5) & 15;
  int row = idx >> 9;
  int s = row & 2047;
  float p = (float)pos[s];
  float freq = exp2f(-(float)i * (13.287712379549449f / 32.0f));
  float ang = p * freq;
  float sn, cs;
  sincosf(ang, &sn, &cs);
  size_t base = (size_t)row * 3072 + h * 64 + 2 * i;
  bf16x2 q = *(bf16x2*)(qkv + base);
  bf16x2 k = *(bf16x2*)(qkv + base + 1024);
  float q1 = (float)q[0], q2 = (float)q[1];
  float k1 = (float)k[0], k2 = (float)k[1];
  bf16x2 qo, ko;
  qo[0] = (bf16)(q1 * cs - q2 * sn);
  qo[1] = (bf16)(q1 * sn + q2 * cs);
  ko[0] = (bf16)(k1 * cs - k2 * sn);
  ko[1] = (bf16)(k1 * sn + k2 * cs);
  *(bf16x2*)(qkv + base) = qo;
  *(bf16x2*)(qkv + base + 1024) = ko;
}

// ---------------- causal flash attention v3 ----------------
// grid: (S/128, B*H), 256 thr = 4 waves; wave w owns q rows [q0+32w, q0+32w+32) (2 col-frags).
// KV tile = 64 keys. K staged via global_load_lds (linear LDS + source-XOR swizzle),
// V^T scatter-staged with chunk-XOR swizzle. Swapped-operand MFMA, lane-local softmax.
__global__ __launch_bounds__(256, 4) void fa_causal(const bf16* __restrict__ qkv,
                                                    bf16* __restrict__ attn) {
  const int bh = blockIdx.y;
  const int b = bh >> 4, h = bh & 15;
  const int q0 = ((int)gridDim.x - 1 - (int)blockIdx.x) * 128;  // heavy blocks first
  const int t = threadIdx.x, w = t >> 6, l = t & 63;
  const int lq = l & 15;       // query col within 16-frag
  const int g = l >> 4;        // lane group
  const int lk = g * 8;
  const int swz = lq & 7;      // row-XOR for swizzled chunk reads

  __shared__ bf16 Ks[64 * 64];      // K [key][d] linear, chunk-swizzled content
  __shared__ bf16 Vt[64 * 64];      // V^T [d][k^((d&7)<<3)]
  __shared__ bf16 Ps[4][32 * 72];   // per-wave P^T [q][k], stride 72; reused as O staging

  const size_t rs = 3072;
  const bf16* Qg = qkv + (size_t)(b * 2048) * rs + h * 64;
  const bf16* Kg = Qg + 1024;
  const bf16* Vg = Qg + 2048;

  const int qrow0 = q0 + w * 32;

  bf16x8 qfr[2][2];
  #pragma unroll
  for (int qi = 0; qi < 2; ++qi)
    #pragma unroll
    for (int kk = 0; kk < 2; ++kk)
      qfr[qi][kk] = *(const bf16x8*)(Qg + (size_t)(qrow0 + qi * 16 + lq) * rs + kk * 32 + lk);

  f32x4 o[4][2] = {};
  float mrow[2] = {-1e30f, -1e30f}, lrow[2] = {0.f, 0.f};

  const int nkt = (q0 + 128) >> 6;
  const int krow_in = l >> 3;            // 0..7 row within 8-row chunk
  const int kcsrc = (l & 7) ^ krow_in;   // pre-swizzled source chunk
  const int vk = t >> 2;                 // 0..63 key row
  const int vd0 = (t & 3) * 16;          // d base

  for (int kt = 0; kt < nkt; ++kt) {
    __syncthreads();
    // ---- stage K (wave w covers rows [16w,16w+16)) via global_load_lds ----
    #pragma unroll
    for (int c = 0; c < 2; ++c) {
      const int rowbase = w * 16 + c * 8;
      const bf16* src = Kg + (size_t)(kt * 64 + rowbase + krow_in) * rs + kcsrc * 8;
      __builtin_amdgcn_global_load_lds(
          (const __attribute__((address_space(1))) void*)src,
          (__attribute__((address_space(3))) void*)(Ks + rowbase * 64), 16, 0, 0);
    }
    // ---- stage V^T (scatter with chunk XOR) ----
    {
      const bf16* vsrc = Vg + (size_t)(kt * 64 + vk) * rs + vd0;
      bf16x8 v0 = *(const bf16x8*)(vsrc);
      bf16x8 v1 = *(const bf16x8*)(vsrc + 8);
      #pragma unroll
      for (int e = 0; e < 8; ++e)
        Vt[(vd0 + e) * 64 + (vk ^ (e << 3))] = v0[e];
      #pragma unroll
      for (int e = 0; e < 8; ++e)
        Vt[(vd0 + 8 + e) * 64 + (vk ^ (e << 3))] = v1[e];
    }
    __syncthreads();

    if (kt * 64 <= qrow0 + 31) {  // wave-uniform causal skip
      // ---- QK^T swapped: S^T[64k][32q] ----
      f32x4 sc0[4] = {}, sc1[4] = {};
      __builtin_amdgcn_s_setprio(1);
      #pragma unroll
      for (int kf = 0; kf < 4; ++kf) {
        const int krow = kf * 16 + lq;
        bf16x8 kb0 = *(const bf16x8*)(&Ks[krow * 64 + ((0 + g) ^ swz) * 8]);
        bf16x8 kb1 = *(const bf16x8*)(&Ks[krow * 64 + ((4 + g) ^ swz) * 8]);
        sc0[kf] = MFMA16(kb0, qfr[0][0], sc0[kf]);
        sc0[kf] = MFMA16(kb1, qfr[0][1], sc0[kf]);
        sc1[kf] = MFMA16(kb0, qfr[1][0], sc1[kf]);
        sc1[kf] = MFMA16(kb1, qfr[1][1], sc1[kf]);
      }
      __builtin_amdgcn_s_setprio(0);

      // ---- online softmax per q-frag (lane-local, 2 shfls per reduction) ----
      #pragma unroll
      for (int qi = 0; qi < 2; ++qi) {
        f32x4* sc = qi ? sc1 : sc0;
        const int qg = qrow0 + qi * 16 + lq;
        float pv[16];
        float mx = -1e30f;
        #pragma unroll
        for (int kf = 0; kf < 4; ++kf)
          #pragma unroll
          for (int r = 0; r < 4; ++r) {
            int key = kt * 64 + kf * 16 + g * 4 + r;
            float s = (key <= qg) ? sc[kf][r] * 0.125f : -1e30f;
            pv[kf * 4 + r] = s;
            mx = fmaxf(mx, s);
          }
        mx = fmaxf(mx, __shfl_xor(mx, 16, 64));
        mx = fmaxf(mx, __shfl_xor(mx, 32, 64));
        float mnew = fmaxf(mrow[qi], mx);
        float al = __expf(mrow[qi] - mnew);
        float rsum = 0.f;
        #pragma unroll
        for (int i = 0; i < 16; ++i) {
          float p = __expf(pv[i] - mnew);
          pv[i] = p;
          rsum += p;
        }
        rsum += __shfl_xor(rsum, 16, 64);
        rsum += __shfl_xor(rsum, 32, 64);
        lrow[qi] = lrow[qi] * al + rsum;
        mrow[qi] = mnew;

        #pragma unroll
        for (int fd = 0; fd < 4; ++fd)
          #pragma unroll
          for (int r = 0; r < 4; ++r) o[fd][qi][r] *= al;

        // P^T rows (wave-local staging)
        #pragma unroll
        for (int kf = 0; kf < 4; ++kf) {
          bf16x4v pk;
          #pragma unroll
          for (int r = 0; r < 4; ++r) pk[r] = (bf16)pv[kf * 4 + r];
          *(bf16x4v*)(&Ps[w][(qi * 16 + lq) * 72 + kf * 16 + g * 4]) = pk;
        }
      }
      asm volatile("" ::: "memory");

      // ---- PV swapped: O^T[64d][32q] ----
      bf16x8 pf[2][2];
      #pragma unroll
      for (int qi = 0; qi < 2; ++qi)
        #pragma unroll
        for (int ks = 0; ks < 2; ++ks)
          pf[qi][ks] = *(const bf16x8*)(&Ps[w][(qi * 16 + lq) * 72 + ks * 32 + lk]);
      __builtin_amdgcn_s_setprio(1);
      #pragma unroll
      for (int fd = 0; fd < 4; ++fd) {
        const int drow = fd * 16 + lq;
        #pragma unroll
        for (int ks = 0; ks < 2; ++ks) {
          bf16x8 vb = *(const bf16x8*)(&Vt[drow * 64 + ((ks * 4 + g) ^ swz) * 8]);
          o[fd][0] = MFMA16(vb, pf[0][ks], o[fd][0]);
          o[fd][1] = MFMA16(vb, pf[1][ks], o[fd][1]);
        }
      }
      __builtin_amdgcn_s_setprio(0);
    }
  }

  // ---- epilogue: O^T -> [q][d] via per-wave LDS -> coalesced b128 stores ----
  #pragma unroll
  for (int qi = 0; qi < 2; ++qi) {
    float inv = 1.0f / lrow[qi];
    #pragma unroll
    for (int fd = 0; fd < 4; ++fd) {
      bf16x4v ov;
      #pragma unroll
      for (int r = 0; r < 4; ++r) ov[r] = (bf16)(o[fd][qi][r] * inv);
      *(bf16x4v*)(&Ps[w][(qi * 16 + lq) * 72 + fd * 16 + g * 4]) = ov;
    }
  }
  asm volatile("" ::: "memory");
  #pragma unroll
  for (int p = 0; p < 4; ++p) {
    int idx = p * 64 + l;
    int row = idx >> 3, c8 = idx & 7;
    bf16x8 v = *(const bf16x8*)(&Ps[w][row * 72 + c8 * 8]);
    *(bf16x8*)(&attn[(size_t)(b * 2048 + q0 + w * 32 + row) * 1024 + h * 64 + c8 * 8]) = v;
  }
}

// ---------------- launch ----------------
extern "C" void kernel_launch(void* const* d_in, const int* in_sizes, int n_in,
                              void* d_out, int out_size, void* d_ws, size_t ws_size,
                              hipStream_t stream) {
  const float* x = (const float*)d_in[0];
  const int* pos = (const int*)d_in[1];
  const float* w_qkv = (const float*)d_in[2];
  const float* w_out = (const float*)d_in[3];
  float* out = (float*)d_out;

  char* ws = (char*)d_ws;
  bf16* xb   = (bf16*)(ws);
  bf16* wqb  = (bf16*)(ws + (8u << 20));
  bf16* wob  = (bf16*)(ws + (14u << 20));
  bf16* qkv  = (bf16*)(ws + (16u << 20));
  bf16* attn = (bf16*)(ws + (40u << 20));

  cast_kernel<<<4096, 256, 0, stream>>>(x, xb, 4194304 / 4);
  cast_kernel<<<3072, 256, 0, stream>>>(w_qkv, wqb, 3145728 / 4);
  cast_kernel<<<1024, 256, 0, stream>>>(w_out, wob, 1048576 / 4);

  dim3 g1(3072 / 128, 4096 / 128);
  gemm_bt<false><<<g1, 256, 0, stream>>>(xb, wqb, (void*)qkv, 4096, 3072, 1024);

  rope_kernel<<<8192, 256, 0, stream>>>(qkv, pos);

  dim3 gfa(2048 / 128, 32);
  fa_causal<<<gfa, 256, 0, stream>>>(qkv, attn);

  dim3 g2(1024 / 128, 4096 / 128);
  gemm_bt<true><<<g2, 256, 0, stream>>>(attn, wob, (void*)out, 4096, 1024, 1024);
}

// Round 4
// 163.570 us; speedup vs baseline: 1.8211x; 1.0801x over previous
//
#include <hip/hip_runtime.h>

using bf16 = __bf16;
typedef __bf16 bf16x2 __attribute__((ext_vector_type(2)));
typedef __bf16 bf16x4v __attribute__((ext_vector_type(4)));
typedef __bf16 bf16x8 __attribute__((ext_vector_type(8)));
typedef float f32x4 __attribute__((ext_vector_type(4)));
typedef float floatx4 __attribute__((ext_vector_type(4)));

#define MFMA16(a, b, c) __builtin_amdgcn_mfma_f32_16x16x32_bf16((a), (b), (c), 0, 0, 0)

__device__ __forceinline__ float exp2a(float x) {
#if __has_builtin(__builtin_amdgcn_exp2f)
  return __builtin_amdgcn_exp2f(x);
#else
  float r;
  asm("v_exp_f32 %0, %1" : "=v"(r) : "v"(x));
  return r;
#endif
}

// ---------------- cast fp32 -> bf16 (4 elems/thread) ----------------
__global__ __launch_bounds__(256) void cast_kernel(const float* __restrict__ in,
                                                   bf16* __restrict__ out, int n4) {
  int i = blockIdx.x * 256 + threadIdx.x;
  if (i >= n4) return;
  floatx4 v = *(const floatx4*)(in + (size_t)i * 4);
  bf16x4v o;
  #pragma unroll
  for (int j = 0; j < 4; ++j) o[j] = (bf16)v[j];
  *(bf16x4v*)(out + (size_t)i * 4) = o;
}

// ---------------- GEMM: C[M][N] = A[M][K] * B[N][K]^T (both bf16, K-contig) ----------------
template <bool OUT_F32>
__global__ __launch_bounds__(256, 2) void gemm_bt(const bf16* __restrict__ A,
                                                  const bf16* __restrict__ B,
                                                  void* __restrict__ Cv,
                                                  int M, int N, int K) {
  __shared__ bf16 As[128 * 32];
  __shared__ bf16 Bs[128 * 32];
  const int t = threadIdx.x;
  const int l = t & 63;
  const int w = t >> 6;
  const int m0 = blockIdx.y * 128;
  const int n0 = blockIdx.x * 128;
  const int wr = (w >> 1) * 64;
  const int wc = (w & 1) * 64;
  const int lr = l & 15;
  const int lk = (l >> 4) * 8;

  f32x4 acc[4][4] = {};

  const int srow = t >> 2;
  const int scol = (t & 3) * 8;

  for (int k0 = 0; k0 < K; k0 += 32) {
    __syncthreads();
    #pragma unroll
    for (int j = 0; j < 2; ++j) {
      const bf16* ga = A + (size_t)(m0 + j * 64 + srow) * K + k0 + scol;
      __builtin_amdgcn_global_load_lds(
          (const __attribute__((address_space(1))) void*)ga,
          (__attribute__((address_space(3))) void*)(As + (j * 64 + srow) * 32 + scol),
          16, 0, 0);
      const bf16* gb = B + (size_t)(n0 + j * 64 + srow) * K + k0 + scol;
      __builtin_amdgcn_global_load_lds(
          (const __attribute__((address_space(1))) void*)gb,
          (__attribute__((address_space(3))) void*)(Bs + (j * 64 + srow) * 32 + scol),
          16, 0, 0);
    }
    __syncthreads();
    bf16x8 af[4], bfr[4];
    #pragma unroll
    for (int i = 0; i < 4; ++i) af[i] = *(const bf16x8*)(As + (wr + i * 16 + lr) * 32 + lk);
    #pragma unroll
    for (int i = 0; i < 4; ++i) bfr[i] = *(const bf16x8*)(Bs + (wc + i * 16 + lr) * 32 + lk);
    #pragma unroll
    for (int i = 0; i < 4; ++i)
      #pragma unroll
      for (int j = 0; j < 4; ++j)
        acc[i][j] = MFMA16(af[i], bfr[j], acc[i][j]);
  }

  const int cr0 = (l >> 4) * 4;
  const int cc = l & 15;
  #pragma unroll
  for (int i = 0; i < 4; ++i) {
    #pragma unroll
    for (int j = 0; j < 4; ++j) {
      int row = m0 + wr + i * 16 + cr0;
      int col = n0 + wc + j * 16 + cc;
      #pragma unroll
      for (int r = 0; r < 4; ++r) {
        if constexpr (OUT_F32)
          ((float*)Cv)[(size_t)(row + r) * N + col] = acc[i][j][r];
        else
          ((bf16*)Cv)[(size_t)(row + r) * N + col] = (bf16)acc[i][j][r];
      }
    }
  }
}

// ---------------- RoPE in-place on q,k of qkv [4096][3072] ----------------
__global__ __launch_bounds__(256) void rope_kernel(bf16* __restrict__ qkv,
                                                   const int* __restrict__ pos) {
  int idx = blockIdx.x * 256 + threadIdx.x;
  int i = idx & 31;
  int h = (idx >> 5) & 15;
  int row = idx >> 9;
  int s = row & 2047;
  float p = (float)pos[s];
  float freq = exp2f(-(float)i * (13.287712379549449f / 32.0f));
  float ang = p * freq;
  float sn, cs;
  sincosf(ang, &sn, &cs);
  size_t base = (size_t)row * 3072 + h * 64 + 2 * i;
  bf16x2 q = *(bf16x2*)(qkv + base);
  bf16x2 k = *(bf16x2*)(qkv + base + 1024);
  float q1 = (float)q[0], q2 = (float)q[1];
  float k1 = (float)k[0], k2 = (float)k[1];
  bf16x2 qo, ko;
  qo[0] = (bf16)(q1 * cs - q2 * sn);
  qo[1] = (bf16)(q1 * sn + q2 * cs);
  ko[0] = (bf16)(k1 * cs - k2 * sn);
  ko[1] = (bf16)(k1 * sn + k2 * cs);
  *(bf16x2*)(qkv + base) = qo;
  *(bf16x2*)(qkv + base + 1024) = ko;
}

// ---------------- causal flash attention v4: double-buffered staging ----------------
// grid: (S/128, B*H), 256 thr = 4 waves; wave w owns q rows [q0+32w, q0+32w+32).
// KV tile 64. K via global_load_lds (source-XOR swizzle); V via reg-staged scatter with
// 2-way-free XOR swizzle. Next tile's loads issue before current compute (latency hidden);
// one barrier per tile. Swapped-operand MFMA, lane-local exp2 softmax, defer-max.
__global__ __launch_bounds__(256, 4) void fa_causal(const bf16* __restrict__ qkv,
                                                    bf16* __restrict__ attn) {
  const int bh = blockIdx.y;
  const int b = bh >> 4, h = bh & 15;
  const int q0 = ((int)gridDim.x - 1 - (int)blockIdx.x) * 128;  // heavy blocks first
  const int t = threadIdx.x, w = t >> 6, l = t & 63;
  const int lq = l & 15;
  const int g = l >> 4;
  const int lk = g * 8;
  const int swz = lq & 7;

  __shared__ bf16 Ks[2][64 * 64];
  __shared__ bf16 Vt[2][64 * 64];
  __shared__ bf16 Ps[4][32 * 72];

  const size_t rs = 3072;
  const bf16* Qg = qkv + (size_t)(b * 2048) * rs + h * 64;
  const bf16* Kg = Qg + 1024;
  const bf16* Vg = Qg + 2048;

  const int qrow0 = q0 + w * 32;

  bf16x8 qfr[2][2];
  #pragma unroll
  for (int qi = 0; qi < 2; ++qi)
    #pragma unroll
    for (int kk = 0; kk < 2; ++kk)
      qfr[qi][kk] = *(const bf16x8*)(Qg + (size_t)(qrow0 + qi * 16 + lq) * rs + kk * 32 + lk);

  f32x4 o[4][2] = {};
  float mrow[2] = {-1e30f, -1e30f}, lrow[2] = {0.f, 0.f};
  const float SC = 0.125f * 1.44269504088896f;  // scale * log2(e)

  const int nkt = (q0 + 128) >> 6;
  const int krow_in = l >> 3;
  const int kcsrc = (l & 7) ^ krow_in;
  const int vk = t >> 2;           // 0..63 key row (coalesced global read)
  const int vd0 = (t & 3) * 16;    // d base
  const int vx = vd0 >> 4;         // 0..3

  bf16x8 va, vb2;

  #define STAGE_K(KT, BUF)                                                              \
    {                                                                                   \
      _Pragma("unroll")                                                                 \
      for (int c = 0; c < 2; ++c) {                                                     \
        const int rowbase = w * 16 + c * 8;                                             \
        const bf16* src = Kg + (size_t)((KT)*64 + rowbase + krow_in) * rs + kcsrc * 8;  \
        __builtin_amdgcn_global_load_lds(                                               \
            (const __attribute__((address_space(1))) void*)src,                         \
            (__attribute__((address_space(3))) void*)(&Ks[BUF][rowbase * 64]), 16, 0, 0); \
      }                                                                                 \
    }
  #define LOAD_V(KT)                                                       \
    {                                                                      \
      const bf16* vsrc = Vg + (size_t)((KT)*64 + vk) * rs + vd0;           \
      va = *(const bf16x8*)(vsrc);                                         \
      vb2 = *(const bf16x8*)(vsrc + 8);                                    \
    }
  #define WRITE_V(BUF)                                                     \
    {                                                                      \
      _Pragma("unroll")                                                    \
      for (int e = 0; e < 8; ++e) {                                        \
        int pp = vk ^ (e << 3) ^ (vx << 4);                                \
        Vt[BUF][(vd0 + e) * 64 + pp] = va[e];                              \
        Vt[BUF][(vd0 + 8 + e) * 64 + pp] = vb2[e];                         \
      }                                                                    \
    }

  STAGE_K(0, 0)
  LOAD_V(0)
  WRITE_V(0)
  __syncthreads();

  int cur = 0;
  for (int kt = 0; kt < nkt; ++kt) {
    const bool pf = (kt + 1 < nkt);
    if (pf) {
      STAGE_K(kt + 1, cur ^ 1)
      LOAD_V(kt + 1)
    }

    if (kt * 64 <= qrow0 + 31) {  // wave-uniform causal skip
      const bf16* Kc = Ks[cur];
      const bf16* Vc = Vt[cur];

      f32x4 sc0[4] = {}, sc1[4] = {};
      __builtin_amdgcn_s_setprio(1);
      #pragma unroll
      for (int kf = 0; kf < 4; ++kf) {
        const int krow = kf * 16 + lq;
        bf16x8 kb0 = *(const bf16x8*)(&Kc[krow * 64 + ((0 + g) ^ swz) * 8]);
        bf16x8 kb1 = *(const bf16x8*)(&Kc[krow * 64 + ((4 + g) ^ swz) * 8]);
        sc0[kf] = MFMA16(kb0, qfr[0][0], sc0[kf]);
        sc0[kf] = MFMA16(kb1, qfr[0][1], sc0[kf]);
        sc1[kf] = MFMA16(kb0, qfr[1][0], sc1[kf]);
        sc1[kf] = MFMA16(kb1, qfr[1][1], sc1[kf]);
      }
      __builtin_amdgcn_s_setprio(0);

      #pragma unroll
      for (int qi = 0; qi < 2; ++qi) {
        f32x4* sc = qi ? sc1 : sc0;
        const int qg = qrow0 + qi * 16 + lq;
        float pv[16];
        float mx = -1e30f;
        #pragma unroll
        for (int kf = 0; kf < 4; ++kf)
          #pragma unroll
          for (int r = 0; r < 4; ++r) {
            int key = kt * 64 + kf * 16 + g * 4 + r;
            float s = (key <= qg) ? sc[kf][r] * SC : -1e30f;
            pv[kf * 4 + r] = s;
            mx = fmaxf(mx, s);
          }
        mx = fmaxf(mx, __shfl_xor(mx, 16, 64));
        mx = fmaxf(mx, __shfl_xor(mx, 32, 64));
        if (!__all(mx <= mrow[qi])) {  // defer-max: rescale only when max grew
          float mnew = fmaxf(mrow[qi], mx);
          float al = exp2a(mrow[qi] - mnew);
          lrow[qi] *= al;
          #pragma unroll
          for (int fd = 0; fd < 4; ++fd)
            #pragma unroll
            for (int r = 0; r < 4; ++r) o[fd][qi][r] *= al;
          mrow[qi] = mnew;
        }
        float rsum = 0.f;
        #pragma unroll
        for (int i = 0; i < 16; ++i) {
          float p = exp2a(pv[i] - mrow[qi]);
          pv[i] = p;
          rsum += p;
        }
        rsum += __shfl_xor(rsum, 16, 64);
        rsum += __shfl_xor(rsum, 32, 64);
        lrow[qi] += rsum;

        #pragma unroll
        for (int kf = 0; kf < 4; ++kf) {
          bf16x4v pk;
          #pragma unroll
          for (int r = 0; r < 4; ++r) pk[r] = (bf16)pv[kf * 4 + r];
          *(bf16x4v*)(&Ps[w][(qi * 16 + lq) * 72 + kf * 16 + g * 4]) = pk;
        }
      }
      asm volatile("" ::: "memory");

      bf16x8 pf2[2][2];
      #pragma unroll
      for (int qi = 0; qi < 2; ++qi)
        #pragma unroll
        for (int ks = 0; ks < 2; ++ks)
          pf2[qi][ks] = *(const bf16x8*)(&Ps[w][(qi * 16 + lq) * 72 + ks * 32 + lk]);
      __builtin_amdgcn_s_setprio(1);
      #pragma unroll
      for (int fd = 0; fd < 4; ++fd) {
        const int drow = fd * 16 + lq;
        #pragma unroll
        for (int ks = 0; ks < 2; ++ks) {
          bf16x8 vb = *(const bf16x8*)(&Vc[drow * 64 + (((ks * 4 + g) ^ swz ^ (fd << 1)) * 8)]);
          o[fd][0] = MFMA16(vb, pf2[0][ks], o[fd][0]);
          o[fd][1] = MFMA16(vb, pf2[1][ks], o[fd][1]);
        }
      }
      __builtin_amdgcn_s_setprio(0);
    }

    if (pf) {
      WRITE_V(cur ^ 1)   // vmcnt wait lands here, hidden under compute
      __syncthreads();   // publishes tile kt+1 (drains gll too)
    }
    cur ^= 1;
  }

  // ---- epilogue: O^T -> [q][d] via per-wave LDS -> coalesced b128 stores ----
  #pragma unroll
  for (int qi = 0; qi < 2; ++qi) {
    float inv = 1.0f / lrow[qi];
    #pragma unroll
    for (int fd = 0; fd < 4; ++fd) {
      bf16x4v ov;
      #pragma unroll
      for (int r = 0; r < 4; ++r) ov[r] = (bf16)(o[fd][qi][r] * inv);
      *(bf16x4v*)(&Ps[w][(qi * 16 + lq) * 72 + fd * 16 + g * 4]) = ov;
    }
  }
  asm volatile("" ::: "memory");
  #pragma unroll
  for (int p = 0; p < 4; ++p) {
    int idx = p * 64 + l;
    int row = idx >> 3, c8 = idx & 7;
    bf16x8 v = *(const bf16x8*)(&Ps[w][row * 72 + c8 * 8]);
    *(bf16x8*)(&attn[(size_t)(b * 2048 + q0 + w * 32 + row) * 1024 + h * 64 + c8 * 8]) = v;
  }
}

// ---------------- launch ----------------
extern "C" void kernel_launch(void* const* d_in, const int* in_sizes, int n_in,
                              void* d_out, int out_size, void* d_ws, size_t ws_size,
                              hipStream_t stream) {
  const float* x = (const float*)d_in[0];
  const int* pos = (const int*)d_in[1];
  const float* w_qkv = (const float*)d_in[2];
  const float* w_out = (const float*)d_in[3];
  float* out = (float*)d_out;

  char* ws = (char*)d_ws;
  bf16* xb   = (bf16*)(ws);
  bf16* wqb  = (bf16*)(ws + (8u << 20));
  bf16* wob  = (bf16*)(ws + (14u << 20));
  bf16* qkv  = (bf16*)(ws + (16u << 20));
  bf16* attn = (bf16*)(ws + (40u << 20));

  cast_kernel<<<4096, 256, 0, stream>>>(x, xb, 4194304 / 4);
  cast_kernel<<<3072, 256, 0, stream>>>(w_qkv, wqb, 3145728 / 4);
  cast_kernel<<<1024, 256, 0, stream>>>(w_out, wob, 1048576 / 4);

  dim3 g1(3072 / 128, 4096 / 128);
  gemm_bt<false><<<g1, 256, 0, stream>>>(xb, wqb, (void*)qkv, 4096, 3072, 1024);

  rope_kernel<<<8192, 256, 0, stream>>>(qkv, pos);

  dim3 gfa(2048 / 128, 32);
  fa_causal<<<gfa, 256, 0, stream>>>(qkv, attn);

  dim3 g2(1024 / 128, 4096 / 128);
  gemm_bt<true><<<g2, 256, 0, stream>>>(attn, wob, (void*)out, 4096, 1024, 1024);
}